// Round 1
// baseline (530.254 us; speedup 1.0000x reference)
//
#include <hip/hip_runtime.h>
#include <math.h>

// Problem constants (fixed by the reference)
#define NB   16      // batch
#define NCH  64      // C
#define NH   64      // H
#define NW   64      // W
#define NL   4096    // H*W
#define DIN  128     // D_INNER
#define DST  16      // D_STATE
#define DTR  4       // DT_RANK
#define NJ   256     // 2*D_INNER
#define NCHK 64      // scan chunks
#define CT   64      // chunk length (NCHK*CT == NL)

// Workspace region size (floats). 5 regions of 8.4M + small tail = ~168 MB.
#define RSZ 8388608ull

// ---------------------------------------------------------------------------
// prep: A = -exp(A_log); transpose conv weights (co,ci,kh,kw) -> (ci,k9,co)
// ---------------------------------------------------------------------------
__global__ void k_prep(const float* __restrict__ w1, const float* __restrict__ w2,
                       const float* __restrict__ alog,
                       float* __restrict__ wT1, float* __restrict__ wT2,
                       float* __restrict__ A1) {
  int i = blockIdx.x * 256 + threadIdx.x;
  if (i < NCH * NCH * 9) {
    int ci = i / 576;
    int r  = i - ci * 576;
    int k  = r >> 6;
    int co = r & 63;
    wT1[i] = w1[co * 576 + ci * 9 + k];
    wT2[i] = w2[co * 576 + ci * 9 + k];
  }
  if (i < DIN * DST) A1[i] = -__expf(alog[i]);
}

// ---------------------------------------------------------------------------
// conv3x3 + bias + leaky ReLU (fp32 direct conv)
// grid: (H/4, 2 co-halves, B), 256 threads (4 waves).
// Each wave owns 8 output channels (uniform -> weights come in as s_loads);
// each lane owns 4 pixels (row r = lane>>4 of 4, cols tx*4..tx*4+3).
// Only the input tile goes through LDS (16 ci x 6 rows x 68 cols, 26 KB).
// ---------------------------------------------------------------------------
__global__ __launch_bounds__(256) void k_conv(
    const float* __restrict__ in, const float* __restrict__ wT,
    const float* __restrict__ bias, float* __restrict__ out) {
  __shared__ float xs[16 * 6 * 68];
  const int tid   = threadIdx.x;
  const int b     = blockIdx.z;
  const int h0    = blockIdx.x * 4;
  const int chalf = blockIdx.y;
  const int wv    = __builtin_amdgcn_readfirstlane(tid >> 6);
  const int lane  = tid & 63;
  const int r     = lane >> 4;
  const int tx    = lane & 15;
  const int co0   = chalf * 32 + wv * 8;

  float acc[8][4];
#pragma unroll
  for (int j = 0; j < 8; ++j)
#pragma unroll
    for (int p = 0; p < 4; ++p) acc[j][p] = 0.f;

  for (int cc = 0; cc < 4; ++cc) {
    const int ci0 = cc * 16;
    __syncthreads();
    for (int e = tid; e < 6528; e += 256) {
      int ci  = e / 408;            // 6*68
      int rem = e - ci * 408;
      int rr  = rem / 68;
      int col = rem - rr * 68;
      int h   = h0 - 1 + rr;
      int wc  = col - 1;
      float v = 0.f;
      if (h >= 0 && h < NH && wc >= 0 && wc < NW)
        v = in[((b * NCH + ci0 + ci) * NH + h) * NW + wc];
      xs[e] = v;
    }
    __syncthreads();
    const float* wp0 = wT + ci0 * 576 + co0;
#pragma unroll 2
    for (int ci = 0; ci < 16; ++ci) {
      const float* xrow = &xs[ci * 408];
#pragma unroll
      for (int kh = 0; kh < 3; ++kh) {
        const float* xr = &xrow[(r + kh) * 68 + tx * 4];
        float xv[8];
        *(float4*)&xv[0] = *(const float4*)&xr[0];
        *(float4*)&xv[4] = *(const float4*)&xr[4];
        const float* wp = wp0 + ci * 576 + kh * 192;
#pragma unroll
        for (int kw = 0; kw < 3; ++kw) {
          const float* wk = wp + kw * 64;
#pragma unroll
          for (int j = 0; j < 8; ++j) {
            const float wj = wk[j];
            acc[j][0] = fmaf(xv[kw + 0], wj, acc[j][0]);
            acc[j][1] = fmaf(xv[kw + 1], wj, acc[j][1]);
            acc[j][2] = fmaf(xv[kw + 2], wj, acc[j][2]);
            acc[j][3] = fmaf(xv[kw + 3], wj, acc[j][3]);
          }
        }
      }
    }
  }
#pragma unroll
  for (int j = 0; j < 8; ++j) {
    const float bv = bias[co0 + j];
    float4 o;
    float* po = (float*)&o;
#pragma unroll
    for (int p = 0; p < 4; ++p) {
      float v = acc[j][p] + bv;
      po[p] = v >= 0.f ? v : 0.01f * v;
    }
    *(float4*)&out[((size_t)(b * NCH + co0 + j) * NH + h0 + r) * NW + tx * 4] = o;
  }
}

// ---------------------------------------------------------------------------
// in_proj: xz[b,l,j] = sum_c Y[b,c,l] * Win[c,j]; j<128 -> xpre[b,j,l], else z
// grid: (L/64, 4 j-quarters, B), 256 threads; wave owns 16 j (uniform weights)
// ---------------------------------------------------------------------------
__global__ __launch_bounds__(256) void k_inproj(
    const float* __restrict__ Y, const float* __restrict__ Win,
    float* __restrict__ xpre, float* __restrict__ z) {
  const int tid  = threadIdx.x;
  const int wv   = __builtin_amdgcn_readfirstlane(tid >> 6);
  const int lane = tid & 63;
  const int b    = blockIdx.z;
  const int l    = blockIdx.x * 64 + lane;
  const int j0   = blockIdx.y * 64 + wv * 16;
  const float* yp = Y + (size_t)b * NCH * NL + l;
  const float* wp = Win + j0;
  float acc[16];
#pragma unroll
  for (int j = 0; j < 16; ++j) acc[j] = 0.f;
  for (int c = 0; c < NCH; ++c) {
    const float yv = yp[(size_t)c * NL];
    const float* w = wp + c * NJ;
#pragma unroll
    for (int j = 0; j < 16; ++j) acc[j] = fmaf(yv, w[j], acc[j]);
  }
  float* outp = (j0 < DIN) ? (xpre + ((size_t)b * DIN + j0) * NL + l)
                           : (z + ((size_t)b * DIN + (j0 - DIN)) * NL + l);
#pragma unroll
  for (int j = 0; j < 16; ++j) outp[(size_t)j * NL] = acc[j];
}

// ---------------------------------------------------------------------------
// causal depthwise conv1d (k=4) + bias + silu:  u[b,d,l]
// grid: (L/1024, B*DIN), 256 threads, 4 l per thread
// ---------------------------------------------------------------------------
__global__ void k_dwconv(const float* __restrict__ xpre,
                         const float* __restrict__ w1d,
                         const float* __restrict__ b1d,
                         float* __restrict__ u) {
  const int bd = blockIdx.y;
  const int d  = bd & (DIN - 1);
  const int l0 = (blockIdx.x * 256 + threadIdx.x) * 4;
  const float* xp = xpre + (size_t)bd * NL;
  const float w0 = w1d[d * 4 + 0], w1 = w1d[d * 4 + 1];
  const float w2 = w1d[d * 4 + 2], w3 = w1d[d * 4 + 3];
  const float bb = b1d[d];
  float x[8];
  if (l0 >= 4) {
    *(float4*)&x[0] = *(const float4*)&xp[l0 - 4];
  } else {
    x[0] = x[1] = x[2] = x[3] = 0.f;
  }
  *(float4*)&x[4] = *(const float4*)&xp[l0];
  float4 o;
  float* po = (float*)&o;
#pragma unroll
  for (int p = 0; p < 4; ++p) {
    float v = bb;
    v = fmaf(w0, x[p + 1], v);
    v = fmaf(w1, x[p + 2], v);
    v = fmaf(w2, x[p + 3], v);
    v = fmaf(w3, x[p + 4], v);
    po[p] = __fdividef(v, 1.f + __expf(-v));   // silu
  }
  *(float4*)&u[(size_t)bd * NL + l0] = o;
}

// ---------------------------------------------------------------------------
// x_proj + split + dt_proj + softplus:
//   dbc[36] per (b,l); BmT[b,l,n], CmT[b,l,n] (n contiguous for scalar loads
//   in the scan), delta[b,d,l] = softplus(dt @ Wdt + bdt)
// grid: (B*L/256), 256 threads, thread = one (b,l)
// ---------------------------------------------------------------------------
__global__ __launch_bounds__(256) void k_xproj(
    const float* __restrict__ u, const float* __restrict__ Wxp,
    const float* __restrict__ Wdt, const float* __restrict__ bdt,
    float* __restrict__ BmT, float* __restrict__ CmT,
    float* __restrict__ delta) {
  const int g = blockIdx.x * 256 + threadIdx.x;
  const int b = g >> 12;
  const int l = g & (NL - 1);
  const float* up = u + (size_t)b * DIN * NL + l;
  float dbc[36];
#pragma unroll
  for (int j = 0; j < 36; ++j) dbc[j] = 0.f;
  for (int d = 0; d < DIN; ++d) {
    const float uv = up[(size_t)d * NL];
    const float* w = Wxp + d * 36;
#pragma unroll
    for (int j = 0; j < 36; ++j) dbc[j] = fmaf(uv, w[j], dbc[j]);
  }
  float* bp = BmT + (size_t)g * 16;
  float* cp = CmT + (size_t)g * 16;
#pragma unroll
  for (int n4 = 0; n4 < 4; ++n4) {
    *(float4*)&bp[n4 * 4] = make_float4(dbc[4 + n4 * 4], dbc[5 + n4 * 4],
                                        dbc[6 + n4 * 4], dbc[7 + n4 * 4]);
    *(float4*)&cp[n4 * 4] = make_float4(dbc[20 + n4 * 4], dbc[21 + n4 * 4],
                                        dbc[22 + n4 * 4], dbc[23 + n4 * 4]);
  }
  float* dp = delta + (size_t)b * DIN * NL + l;
  for (int d = 0; d < DIN; ++d) {
    float s = bdt[d];
#pragma unroll
    for (int r2 = 0; r2 < DTR; ++r2) s = fmaf(dbc[r2], Wdt[r2 * DIN + d], s);
    // softplus (accurate form)
    const float sp = fmaxf(s, 0.f) + log1pf(expf(-fabsf(s)));
    dp[(size_t)d * NL] = sp;
  }
}

// ---------------------------------------------------------------------------
// scan phase 1: per-chunk transition P = prod(a), Q = sum(prefix a * db * B)
// grid: (NCHK, B), 128 threads, thread = d, 16 states (n) in registers
// ---------------------------------------------------------------------------
__global__ __launch_bounds__(128) void k_scan1(
    const float* __restrict__ delta, const float* __restrict__ u,
    const float* __restrict__ BmT, const float* __restrict__ A1,
    float* __restrict__ P, float* __restrict__ Q) {
  const int d  = threadIdx.x;
  const int b  = blockIdx.y;
  const int ck = blockIdx.x;
  const int t0 = ck * CT;
  const float* dp = delta + ((size_t)b * DIN + d) * NL + t0;
  const float* up = u + ((size_t)b * DIN + d) * NL + t0;
  const float* bp = BmT + ((size_t)b * NL + t0) * 16;
  float a1[DST], Pr[DST], Qr[DST];
#pragma unroll
  for (int n = 0; n < 16; n += 4) {
    float4 t = *(const float4*)&A1[d * 16 + n];
    a1[n] = t.x; a1[n + 1] = t.y; a1[n + 2] = t.z; a1[n + 3] = t.w;
  }
#pragma unroll
  for (int n = 0; n < 16; ++n) { Pr[n] = 1.f; Qr[n] = 0.f; }
  for (int tt = 0; tt < CT; tt += 4) {
    const float4 dv = *(const float4*)(dp + tt);
    const float4 uv = *(const float4*)(up + tt);
    const float* dvf = (const float*)&dv;
    const float* uvf = (const float*)&uv;
#pragma unroll
    for (int q = 0; q < 4; ++q) {
      const float ld = dvf[q];
      const float db = ld * uvf[q];
      const float* br = bp + (tt + q) * 16;
#pragma unroll
      for (int n = 0; n < 16; ++n) {
        const float a = __expf(ld * a1[n]);
        Pr[n] *= a;
        Qr[n] = fmaf(a, Qr[n], db * br[n]);
      }
    }
  }
  const size_t o = (((size_t)b * NCHK + ck) * DIN + d) * 16;
#pragma unroll
  for (int n4 = 0; n4 < 4; ++n4) {
    *(float4*)&P[o + n4 * 4] = make_float4(Pr[n4 * 4], Pr[n4 * 4 + 1],
                                           Pr[n4 * 4 + 2], Pr[n4 * 4 + 3]);
    *(float4*)&Q[o + n4 * 4] = make_float4(Qr[n4 * 4], Qr[n4 * 4 + 1],
                                           Qr[n4 * 4 + 2], Qr[n4 * 4 + 3]);
  }
}

// ---------------------------------------------------------------------------
// scan phase 2: sequential combine over chunks -> H0[b,ck,d,n] (h at chunk in)
// grid: (B), 128 threads, thread = d
// ---------------------------------------------------------------------------
__global__ __launch_bounds__(128) void k_scan2(
    const float* __restrict__ P, const float* __restrict__ Q,
    float* __restrict__ H0) {
  const int d = threadIdx.x;
  const int b = blockIdx.x;
  float h[DST];
#pragma unroll
  for (int n = 0; n < 16; ++n) h[n] = 0.f;
  const size_t stride = (size_t)DIN * 16;
  const float* pp = P + ((size_t)b * NCHK * DIN + d) * 16;
  const float* qp = Q + ((size_t)b * NCHK * DIN + d) * 16;
  float* hp = H0 + ((size_t)b * NCHK * DIN + d) * 16;
  for (int c = 0; c < NCHK; ++c) {
    float4 pv[4], qv[4];
#pragma unroll
    for (int k = 0; k < 4; ++k) {
      pv[k] = *(const float4*)(pp + k * 4);
      qv[k] = *(const float4*)(qp + k * 4);
    }
#pragma unroll
    for (int k = 0; k < 4; ++k)
      *(float4*)(hp + k * 4) =
          make_float4(h[4 * k], h[4 * k + 1], h[4 * k + 2], h[4 * k + 3]);
#pragma unroll
    for (int k = 0; k < 4; ++k) {
      const float* pf = (const float*)&pv[k];
      const float* qf = (const float*)&qv[k];
      h[4 * k + 0] = fmaf(pf[0], h[4 * k + 0], qf[0]);
      h[4 * k + 1] = fmaf(pf[1], h[4 * k + 1], qf[1]);
      h[4 * k + 2] = fmaf(pf[2], h[4 * k + 2], qf[2]);
      h[4 * k + 3] = fmaf(pf[3], h[4 * k + 3], qf[3]);
    }
    pp += stride; qp += stride; hp += stride;
  }
}

// ---------------------------------------------------------------------------
// scan phase 3: replay chunk from H0, y = sum_n h*C, epilogue
// (y + u*D) * silu(z) staged in LDS, then fused out_proj GEMM (128 -> 64).
// grid: (NCHK, B), 128 threads
// ---------------------------------------------------------------------------
__global__ __launch_bounds__(128) void k_scan3(
    const float* __restrict__ delta, const float* __restrict__ u,
    const float* __restrict__ zb, const float* __restrict__ BmT,
    const float* __restrict__ CmT, const float* __restrict__ A1,
    const float* __restrict__ H0, const float* __restrict__ Dvec,
    const float* __restrict__ Wout, float* __restrict__ out) {
  __shared__ float yy[DIN * 67];
  const int d  = threadIdx.x;
  const int b  = blockIdx.y;
  const int ck = blockIdx.x;
  const int t0 = ck * CT;
  const float* dp = delta + ((size_t)b * DIN + d) * NL + t0;
  const float* up = u + ((size_t)b * DIN + d) * NL + t0;
  const float* zp = zb + ((size_t)b * DIN + d) * NL + t0;
  const float* bp = BmT + ((size_t)b * NL + t0) * 16;
  const float* cp = CmT + ((size_t)b * NL + t0) * 16;
  float a1[DST], h[DST];
  {
    const size_t ho = (((size_t)b * NCHK + ck) * DIN + d) * 16;
#pragma unroll
    for (int n = 0; n < 16; n += 4) {
      float4 t = *(const float4*)&A1[d * 16 + n];
      a1[n] = t.x; a1[n + 1] = t.y; a1[n + 2] = t.z; a1[n + 3] = t.w;
      float4 hv = *(const float4*)&H0[ho + n];
      h[n] = hv.x; h[n + 1] = hv.y; h[n + 2] = hv.z; h[n + 3] = hv.w;
    }
  }
  const float Dd = Dvec[d];
  for (int tt = 0; tt < CT; tt += 4) {
    const float4 dv = *(const float4*)(dp + tt);
    const float4 uv = *(const float4*)(up + tt);
    const float4 zv = *(const float4*)(zp + tt);
    const float* dvf = (const float*)&dv;
    const float* uvf = (const float*)&uv;
    const float* zvf = (const float*)&zv;
#pragma unroll
    for (int q = 0; q < 4; ++q) {
      const float ld = dvf[q], lu = uvf[q], lz = zvf[q];
      const float db = ld * lu;
      const float* br = bp + (tt + q) * 16;
      const float* cr = cp + (tt + q) * 16;
      float y0 = 0.f, y1 = 0.f, y2 = 0.f, y3 = 0.f;
#pragma unroll
      for (int n = 0; n < 16; n += 4) {
        const float e0 = __expf(ld * a1[n + 0]);
        const float e1 = __expf(ld * a1[n + 1]);
        const float e2 = __expf(ld * a1[n + 2]);
        const float e3 = __expf(ld * a1[n + 3]);
        h[n + 0] = fmaf(e0, h[n + 0], db * br[n + 0]);
        h[n + 1] = fmaf(e1, h[n + 1], db * br[n + 1]);
        h[n + 2] = fmaf(e2, h[n + 2], db * br[n + 2]);
        h[n + 3] = fmaf(e3, h[n + 3], db * br[n + 3]);
        y0 = fmaf(h[n + 0], cr[n + 0], y0);
        y1 = fmaf(h[n + 1], cr[n + 1], y1);
        y2 = fmaf(h[n + 2], cr[n + 2], y2);
        y3 = fmaf(h[n + 3], cr[n + 3], y3);
      }
      const float yt = fmaf(lu, Dd, (y0 + y1) + (y2 + y3));
      const float sz = __fdividef(lz, 1.f + __expf(-lz));
      yy[d * 67 + tt + q] = yt * sz;
    }
  }
  __syncthreads();
  // fused out_proj: out[b,c,t0+lane] = sum_d yy[d][lane] * Wout[d,c]
  const int wv   = __builtin_amdgcn_readfirstlane(d >> 6);
  const int lane = d & 63;
  const int c0   = wv * 32;
  float acc[32];
#pragma unroll
  for (int j = 0; j < 32; ++j) acc[j] = 0.f;
  for (int dd = 0; dd < DIN; ++dd) {
    const float yv = yy[dd * 67 + lane];
    const float* w = Wout + dd * 64 + c0;
#pragma unroll
    for (int j = 0; j < 32; ++j) acc[j] = fmaf(yv, w[j], acc[j]);
  }
  float* op = out + (size_t)b * NCH * NL + t0 + lane;
#pragma unroll
  for (int j = 0; j < 32; ++j) op[(size_t)(c0 + j) * NL] = acc[j];
}

// ---------------------------------------------------------------------------
extern "C" void kernel_launch(void* const* d_in, const int* in_sizes, int n_in,
                              void* d_out, int out_size, void* d_ws,
                              size_t ws_size, hipStream_t stream) {
  (void)in_sizes; (void)n_in; (void)out_size; (void)ws_size;
  const float* x    = (const float*)d_in[0];
  const float* w1   = (const float*)d_in[1];
  const float* b1   = (const float*)d_in[2];
  const float* w2   = (const float*)d_in[3];
  const float* b2   = (const float*)d_in[4];
  const float* win  = (const float*)d_in[5];
  const float* w1d  = (const float*)d_in[6];
  const float* b1d  = (const float*)d_in[7];
  const float* wxp  = (const float*)d_in[8];
  const float* wdt  = (const float*)d_in[9];
  const float* bdt  = (const float*)d_in[10];
  const float* alog = (const float*)d_in[11];
  const float* dvec = (const float*)d_in[12];
  const float* wout = (const float*)d_in[13];
  float* out = (float*)d_out;
  float* ws  = (float*)d_ws;

  // Workspace regions (lifetimes do not overlap within a region):
  float* c1   = ws;                          // R1: conv1 out (dead after conv2)
  float* dl   = ws;                          // R1: delta (written in xproj)
  float* c2   = ws + RSZ;                    // R2: conv2 out (dead after inproj)
  float* bmt  = ws + RSZ;                    // R2: BmT [b,l,16]
  float* cmt  = ws + RSZ + 1048576;          // R2: CmT [b,l,16]
  float* xpre = ws + 2 * RSZ;                // R3: pre-conv1d x (dead after dwconv)
  float* Pb   = ws + 2 * RSZ;                // R3: chunk products
  float* Qb   = ws + 2 * RSZ + 2097152;      // R3
  float* H0b  = ws + 2 * RSZ + 4194304;      // R3
  float* zbuf = ws + 3 * RSZ;                // R4: z
  float* ubuf = ws + 4 * RSZ;                // R5: u (post conv1d+silu)
  float* Ab   = ws + 5 * RSZ;                // A = -exp(A_log)  (2048)
  float* wT1  = Ab + 2048;                   // transposed conv weights
  float* wT2  = wT1 + 36864;
  // total: 5*RSZ + 75776 floats  ~= 168 MB

  k_prep<<<144, 256, 0, stream>>>(w1, w2, alog, wT1, wT2, Ab);
  k_conv<<<dim3(16, 2, 16), 256, 0, stream>>>(x, wT1, b1, c1);
  k_conv<<<dim3(16, 2, 16), 256, 0, stream>>>(c1, wT2, b2, c2);
  k_inproj<<<dim3(64, 4, 16), 256, 0, stream>>>(c2, win, xpre, zbuf);
  k_dwconv<<<dim3(4, NB * DIN), 256, 0, stream>>>(xpre, w1d, b1d, ubuf);
  k_xproj<<<256, 256, 0, stream>>>(ubuf, wxp, wdt, bdt, bmt, cmt, dl);
  k_scan1<<<dim3(NCHK, NB), 128, 0, stream>>>(dl, ubuf, bmt, Ab, Pb, Qb);
  k_scan2<<<NB, 128, 0, stream>>>(Pb, Qb, H0b);
  k_scan3<<<dim3(NCHK, NB), 128, 0, stream>>>(dl, ubuf, zbuf, bmt, cmt, Ab,
                                              H0b, dvec, wout, out);
}

// Round 2
// 407.948 us; speedup vs baseline: 1.2998x; 1.2998x over previous
//
#include <hip/hip_runtime.h>
#include <math.h>

// Problem constants (fixed by the reference)
#define NB   16      // batch
#define NCH  64      // C
#define NH   64      // H
#define NW   64      // W
#define NL   4096    // H*W
#define DIN  128     // D_INNER
#define DST  16      // D_STATE
#define DTR  4       // DT_RANK
#define NJ   256     // 2*D_INNER
#define NCHK 64      // scan chunks
#define CT   64      // chunk length (NCHK*CT == NL)

#define RSZ 8388608ull   // floats per workspace region

// ---------------------------------------------------------------------------
// prep: A = -exp(A_log); transpose conv weights (co,ci,kh,kw) -> (ci,k9,co)
// ---------------------------------------------------------------------------
__global__ void k_prep(const float* __restrict__ w1, const float* __restrict__ w2,
                       const float* __restrict__ alog,
                       float* __restrict__ wT1, float* __restrict__ wT2,
                       float* __restrict__ A1) {
  int i = blockIdx.x * 256 + threadIdx.x;
  if (i < NCH * NCH * 9) {
    int ci = i / 576;
    int r  = i - ci * 576;
    int k  = r >> 6;
    int co = r & 63;
    wT1[i] = w1[co * 576 + ci * 9 + k];
    wT2[i] = w2[co * 576 + ci * 9 + k];
  }
  if (i < DIN * DST) A1[i] = -__expf(alog[i]);
}

// ---------------------------------------------------------------------------
// conv3x3 + bias + leaky ReLU (fp32 direct conv) — unchanged from round 1
// ---------------------------------------------------------------------------
__global__ __launch_bounds__(256) void k_conv(
    const float* __restrict__ in, const float* __restrict__ wT,
    const float* __restrict__ bias, float* __restrict__ out) {
  __shared__ float xs[16 * 6 * 68];
  const int tid   = threadIdx.x;
  const int b     = blockIdx.z;
  const int h0    = blockIdx.x * 4;
  const int chalf = blockIdx.y;
  const int wv    = __builtin_amdgcn_readfirstlane(tid >> 6);
  const int lane  = tid & 63;
  const int r     = lane >> 4;
  const int tx    = lane & 15;
  const int co0   = chalf * 32 + wv * 8;

  float acc[8][4];
#pragma unroll
  for (int j = 0; j < 8; ++j)
#pragma unroll
    for (int p = 0; p < 4; ++p) acc[j][p] = 0.f;

  for (int cc = 0; cc < 4; ++cc) {
    const int ci0 = cc * 16;
    __syncthreads();
    for (int e = tid; e < 6528; e += 256) {
      int ci  = e / 408;            // 6*68
      int rem = e - ci * 408;
      int rr  = rem / 68;
      int col = rem - rr * 68;
      int h   = h0 - 1 + rr;
      int wc  = col - 1;
      float v = 0.f;
      if (h >= 0 && h < NH && wc >= 0 && wc < NW)
        v = in[((b * NCH + ci0 + ci) * NH + h) * NW + wc];
      xs[e] = v;
    }
    __syncthreads();
    const float* wp0 = wT + ci0 * 576 + co0;
#pragma unroll 2
    for (int ci = 0; ci < 16; ++ci) {
      const float* xrow = &xs[ci * 408];
#pragma unroll
      for (int kh = 0; kh < 3; ++kh) {
        const float* xr = &xrow[(r + kh) * 68 + tx * 4];
        float xv[8];
        *(float4*)&xv[0] = *(const float4*)&xr[0];
        *(float4*)&xv[4] = *(const float4*)&xr[4];
        const float* wp = wp0 + ci * 576 + kh * 192;
#pragma unroll
        for (int kw = 0; kw < 3; ++kw) {
          const float* wk = wp + kw * 64;
#pragma unroll
          for (int j = 0; j < 8; ++j) {
            const float wj = wk[j];
            acc[j][0] = fmaf(xv[kw + 0], wj, acc[j][0]);
            acc[j][1] = fmaf(xv[kw + 1], wj, acc[j][1]);
            acc[j][2] = fmaf(xv[kw + 2], wj, acc[j][2]);
            acc[j][3] = fmaf(xv[kw + 3], wj, acc[j][3]);
          }
        }
      }
    }
  }
#pragma unroll
  for (int j = 0; j < 8; ++j) {
    const float bv = bias[co0 + j];
    float4 o;
    float* po = (float*)&o;
#pragma unroll
    for (int p = 0; p < 4; ++p) {
      float v = acc[j][p] + bv;
      po[p] = v >= 0.f ? v : 0.01f * v;
    }
    *(float4*)&out[((size_t)(b * NCH + co0 + j) * NH + h0 + r) * NW + tx * 4] = o;
  }
}

// ---------------------------------------------------------------------------
// in_proj: xz[b,l,j] = sum_c Y[b,c,l] * Win[c,j]
// NEW output layout: xpre[b][l][d] (j<128), z[b][l][d] (j>=128)
// grid: (L/64, 4 j-quarters, B), 256 threads; wave owns 16 consecutive j
// ---------------------------------------------------------------------------
__global__ __launch_bounds__(256) void k_inproj(
    const float* __restrict__ Y, const float* __restrict__ Win,
    float* __restrict__ xpre, float* __restrict__ z) {
  const int tid  = threadIdx.x;
  const int wv   = __builtin_amdgcn_readfirstlane(tid >> 6);
  const int lane = tid & 63;
  const int b    = blockIdx.z;
  const int l    = blockIdx.x * 64 + lane;
  const int j0   = blockIdx.y * 64 + wv * 16;
  const float* yp = Y + (size_t)b * NCH * NL + l;
  const float* wp = Win + j0;
  float acc[16];
#pragma unroll
  for (int j = 0; j < 16; ++j) acc[j] = 0.f;
  for (int c = 0; c < NCH; ++c) {
    const float yv = yp[(size_t)c * NL];
    const float* w = wp + c * NJ;
#pragma unroll
    for (int j = 0; j < 16; ++j) acc[j] = fmaf(yv, w[j], acc[j]);
  }
  float* outp = (j0 < DIN)
      ? (xpre + ((size_t)b * NL + l) * DIN + j0)
      : (z + ((size_t)b * NL + l) * DIN + (j0 - DIN));
#pragma unroll
  for (int j4 = 0; j4 < 4; ++j4)
    *(float4*)&outp[j4 * 4] = make_float4(acc[j4 * 4 + 0], acc[j4 * 4 + 1],
                                          acc[j4 * 4 + 2], acc[j4 * 4 + 3]);
}

// ---------------------------------------------------------------------------
// causal depthwise conv1d (k=4) + bias + silu, [b][l][d] layout.
// thread = one float4 of d for one (b,l). Lanes sweep d then l -> coalesced.
// ---------------------------------------------------------------------------
__global__ void k_dwconv(const float* __restrict__ xpre,
                         const float* __restrict__ w1d,
                         const float* __restrict__ b1d,
                         float* __restrict__ u) {
  const int gid = blockIdx.x * 256 + threadIdx.x;   // total NB*NL*32
  const int d4  = gid & 31;
  const int bl  = gid >> 5;
  const int l   = bl & (NL - 1);
  const int d0  = d4 * 4;
  const float* xp = xpre + (size_t)bl * DIN + d0;
  float4 xk[4];
#pragma unroll
  for (int k = 0; k < 4; ++k) {
    const int lk = l - 3 + k;
    xk[k] = (lk >= 0) ? *(const float4*)&xp[(k - 3) * DIN]
                      : make_float4(0.f, 0.f, 0.f, 0.f);
  }
  float4 o;
  float* po = (float*)&o;
#pragma unroll
  for (int p = 0; p < 4; ++p) {
    const int d = d0 + p;
    float v = b1d[d];
    v = fmaf(w1d[d * 4 + 0], ((const float*)&xk[0])[p], v);
    v = fmaf(w1d[d * 4 + 1], ((const float*)&xk[1])[p], v);
    v = fmaf(w1d[d * 4 + 2], ((const float*)&xk[2])[p], v);
    v = fmaf(w1d[d * 4 + 3], ((const float*)&xk[3])[p], v);
    po[p] = __fdividef(v, 1.f + __expf(-v));   // silu
  }
  *(float4*)&u[(size_t)bl * DIN + d0] = o;
}

// ---------------------------------------------------------------------------
// x_proj + split + dt_proj + softplus, [b][l][d] layouts.
// thread = one (b,l): u row is 128 contiguous floats; delta row contiguous.
// ---------------------------------------------------------------------------
__global__ __launch_bounds__(256) void k_xproj(
    const float* __restrict__ u, const float* __restrict__ Wxp,
    const float* __restrict__ Wdt, const float* __restrict__ bdt,
    float* __restrict__ BmT, float* __restrict__ CmT,
    float* __restrict__ delta) {
  const int g = blockIdx.x * 256 + threadIdx.x;   // g = b*NL + l
  const float* up = u + (size_t)g * DIN;
  float dbc[36];
#pragma unroll
  for (int j = 0; j < 36; ++j) dbc[j] = 0.f;
  for (int d4 = 0; d4 < 32; ++d4) {
    const float4 uv = *(const float4*)&up[d4 * 4];
    const float* uvf = (const float*)&uv;
#pragma unroll
    for (int p = 0; p < 4; ++p) {
      const float* w = Wxp + (d4 * 4 + p) * 36;
      const float uu = uvf[p];
#pragma unroll
      for (int j = 0; j < 36; ++j) dbc[j] = fmaf(uu, w[j], dbc[j]);
    }
  }
  float* bp = BmT + (size_t)g * 16;
  float* cp = CmT + (size_t)g * 16;
#pragma unroll
  for (int n4 = 0; n4 < 4; ++n4) {
    *(float4*)&bp[n4 * 4] = make_float4(dbc[4 + n4 * 4], dbc[5 + n4 * 4],
                                        dbc[6 + n4 * 4], dbc[7 + n4 * 4]);
    *(float4*)&cp[n4 * 4] = make_float4(dbc[20 + n4 * 4], dbc[21 + n4 * 4],
                                        dbc[22 + n4 * 4], dbc[23 + n4 * 4]);
  }
  float* dp = delta + (size_t)g * DIN;
  for (int d4 = 0; d4 < 32; ++d4) {
    float4 o;
    float* po = (float*)&o;
#pragma unroll
    for (int p = 0; p < 4; ++p) {
      const int d = d4 * 4 + p;
      float s = bdt[d];
#pragma unroll
      for (int r2 = 0; r2 < DTR; ++r2) s = fmaf(dbc[r2], Wdt[r2 * DIN + d], s);
      po[p] = fmaxf(s, 0.f) + log1pf(expf(-fabsf(s)));   // softplus
    }
    *(float4*)&dp[d4 * 4] = o;
  }
}

// ---------------------------------------------------------------------------
// scan phase 1: per-chunk P = prod(a), Q = sum(prefix a * db * B)
// [b][l][d] activations: per timestep the wave reads 256B contiguous.
// grid: (NCHK, B), 128 threads, thread = d
// ---------------------------------------------------------------------------
__global__ __launch_bounds__(128) void k_scan1(
    const float* __restrict__ delta, const float* __restrict__ u,
    const float* __restrict__ BmT, const float* __restrict__ A1,
    float* __restrict__ P, float* __restrict__ Q) {
  const int d  = threadIdx.x;
  const int b  = blockIdx.y;
  const int ck = blockIdx.x;
  const int t0 = ck * CT;
  const float* dp = delta + ((size_t)b * NL + t0) * DIN + d;
  const float* up = u + ((size_t)b * NL + t0) * DIN + d;
  const float* bp = BmT + ((size_t)b * NL + t0) * 16;
  float a1[DST], Pr[DST], Qr[DST];
#pragma unroll
  for (int n = 0; n < 16; n += 4) {
    float4 t = *(const float4*)&A1[d * 16 + n];
    a1[n] = t.x; a1[n + 1] = t.y; a1[n + 2] = t.z; a1[n + 3] = t.w;
  }
#pragma unroll
  for (int n = 0; n < 16; ++n) { Pr[n] = 1.f; Qr[n] = 0.f; }
  for (int tt = 0; tt < CT; tt += 4) {
    float ld[4], lu[4];
#pragma unroll
    for (int q = 0; q < 4; ++q) {
      ld[q] = dp[(size_t)(tt + q) * DIN];
      lu[q] = up[(size_t)(tt + q) * DIN];
    }
#pragma unroll
    for (int q = 0; q < 4; ++q) {
      const float db = ld[q] * lu[q];
      const float* br = bp + (tt + q) * 16;
#pragma unroll
      for (int n = 0; n < 16; ++n) {
        const float a = __expf(ld[q] * a1[n]);
        Pr[n] *= a;
        Qr[n] = fmaf(a, Qr[n], db * br[n]);
      }
    }
  }
  const size_t o = (((size_t)b * NCHK + ck) * DIN + d) * 16;
#pragma unroll
  for (int n4 = 0; n4 < 4; ++n4) {
    *(float4*)&P[o + n4 * 4] = make_float4(Pr[n4 * 4], Pr[n4 * 4 + 1],
                                           Pr[n4 * 4 + 2], Pr[n4 * 4 + 3]);
    *(float4*)&Q[o + n4 * 4] = make_float4(Qr[n4 * 4], Qr[n4 * 4 + 1],
                                           Qr[n4 * 4 + 2], Qr[n4 * 4 + 3]);
  }
}

// ---------------------------------------------------------------------------
// scan phase 2: combine over chunks -> H0[b,ck,d,n] (h entering each chunk)
// PARALLEL over (b, d, n): thread = one (d,n) scalar scan. grid (8, B) x 256.
// ---------------------------------------------------------------------------
__global__ __launch_bounds__(256) void k_scan2(
    const float* __restrict__ P, const float* __restrict__ Q,
    float* __restrict__ H0) {
  const int tid = threadIdx.x;
  const int b   = blockIdx.y;
  const int d   = blockIdx.x * 16 + (tid >> 4);
  const int n   = tid & 15;
  const size_t base = ((size_t)b * NCHK * DIN + d) * 16 + n;
  const size_t cs   = (size_t)DIN * 16;   // per-chunk stride
  const float* pp = P + base;
  const float* qp = Q + base;
  float* hp = H0 + base;
  float h = 0.f;
  for (int c = 0; c < NCHK; c += 8) {
    float pv[8], qv[8];
#pragma unroll
    for (int k = 0; k < 8; ++k) {
      pv[k] = pp[k * cs];
      qv[k] = qp[k * cs];
    }
#pragma unroll
    for (int k = 0; k < 8; ++k) {
      hp[k * cs] = h;
      h = fmaf(pv[k], h, qv[k]);
    }
    pp += 8 * cs; qp += 8 * cs; hp += 8 * cs;
  }
}

// ---------------------------------------------------------------------------
// scan phase 3: replay chunk from H0, y = sum_n h*C, epilogue
// (y + u*D) * silu(z) staged in LDS, then fused out_proj GEMM (128 -> 64).
// grid: (NCHK, B), 128 threads
// ---------------------------------------------------------------------------
__global__ __launch_bounds__(128) void k_scan3(
    const float* __restrict__ delta, const float* __restrict__ u,
    const float* __restrict__ zb, const float* __restrict__ BmT,
    const float* __restrict__ CmT, const float* __restrict__ A1,
    const float* __restrict__ H0, const float* __restrict__ Dvec,
    const float* __restrict__ Wout, float* __restrict__ out) {
  __shared__ float yy[DIN * 67];
  const int d  = threadIdx.x;
  const int b  = blockIdx.y;
  const int ck = blockIdx.x;
  const int t0 = ck * CT;
  const float* dp = delta + ((size_t)b * NL + t0) * DIN + d;
  const float* up = u + ((size_t)b * NL + t0) * DIN + d;
  const float* zp = zb + ((size_t)b * NL + t0) * DIN + d;
  const float* bp = BmT + ((size_t)b * NL + t0) * 16;
  const float* cp = CmT + ((size_t)b * NL + t0) * 16;
  float a1[DST], h[DST];
  {
    const size_t ho = (((size_t)b * NCHK + ck) * DIN + d) * 16;
#pragma unroll
    for (int n = 0; n < 16; n += 4) {
      float4 t = *(const float4*)&A1[d * 16 + n];
      a1[n] = t.x; a1[n + 1] = t.y; a1[n + 2] = t.z; a1[n + 3] = t.w;
      float4 hv = *(const float4*)&H0[ho + n];
      h[n] = hv.x; h[n + 1] = hv.y; h[n + 2] = hv.z; h[n + 3] = hv.w;
    }
  }
  const float Dd = Dvec[d];
  for (int tt = 0; tt < CT; tt += 4) {
    float ld4[4], lu4[4], lz4[4];
#pragma unroll
    for (int q = 0; q < 4; ++q) {
      ld4[q] = dp[(size_t)(tt + q) * DIN];
      lu4[q] = up[(size_t)(tt + q) * DIN];
      lz4[q] = zp[(size_t)(tt + q) * DIN];
    }
#pragma unroll
    for (int q = 0; q < 4; ++q) {
      const float ld = ld4[q], lu = lu4[q], lz = lz4[q];
      const float db = ld * lu;
      const float* br = bp + (tt + q) * 16;
      const float* cr = cp + (tt + q) * 16;
      float y0 = 0.f, y1 = 0.f, y2 = 0.f, y3 = 0.f;
#pragma unroll
      for (int n = 0; n < 16; n += 4) {
        const float e0 = __expf(ld * a1[n + 0]);
        const float e1 = __expf(ld * a1[n + 1]);
        const float e2 = __expf(ld * a1[n + 2]);
        const float e3 = __expf(ld * a1[n + 3]);
        h[n + 0] = fmaf(e0, h[n + 0], db * br[n + 0]);
        h[n + 1] = fmaf(e1, h[n + 1], db * br[n + 1]);
        h[n + 2] = fmaf(e2, h[n + 2], db * br[n + 2]);
        h[n + 3] = fmaf(e3, h[n + 3], db * br[n + 3]);
        y0 = fmaf(h[n + 0], cr[n + 0], y0);
        y1 = fmaf(h[n + 1], cr[n + 1], y1);
        y2 = fmaf(h[n + 2], cr[n + 2], y2);
        y3 = fmaf(h[n + 3], cr[n + 3], y3);
      }
      const float yt = fmaf(lu, Dd, (y0 + y1) + (y2 + y3));
      const float sz = __fdividef(lz, 1.f + __expf(-lz));
      yy[d * 67 + tt + q] = yt * sz;
    }
  }
  __syncthreads();
  // fused out_proj: out[b,c,t0+lane] = sum_d yy[d][lane] * Wout[d,c]
  const int wv   = __builtin_amdgcn_readfirstlane(d >> 6);
  const int lane = d & 63;
  const int c0   = wv * 32;
  float acc[32];
#pragma unroll
  for (int j = 0; j < 32; ++j) acc[j] = 0.f;
  for (int dd = 0; dd < DIN; ++dd) {
    const float yv = yy[dd * 67 + lane];
    const float* w = Wout + dd * 64 + c0;
#pragma unroll
    for (int j = 0; j < 32; ++j) acc[j] = fmaf(yv, w[j], acc[j]);
  }
  float* op = out + (size_t)b * NCH * NL + t0 + lane;
#pragma unroll
  for (int j = 0; j < 32; ++j) op[(size_t)(c0 + j) * NL] = acc[j];
}

// ---------------------------------------------------------------------------
extern "C" void kernel_launch(void* const* d_in, const int* in_sizes, int n_in,
                              void* d_out, int out_size, void* d_ws,
                              size_t ws_size, hipStream_t stream) {
  (void)in_sizes; (void)n_in; (void)out_size; (void)ws_size;
  const float* x    = (const float*)d_in[0];
  const float* w1   = (const float*)d_in[1];
  const float* b1   = (const float*)d_in[2];
  const float* w2   = (const float*)d_in[3];
  const float* b2   = (const float*)d_in[4];
  const float* win  = (const float*)d_in[5];
  const float* w1d  = (const float*)d_in[6];
  const float* b1d  = (const float*)d_in[7];
  const float* wxp  = (const float*)d_in[8];
  const float* wdt  = (const float*)d_in[9];
  const float* bdt  = (const float*)d_in[10];
  const float* alog = (const float*)d_in[11];
  const float* dvec = (const float*)d_in[12];
  const float* wout = (const float*)d_in[13];
  float* out = (float*)d_out;
  float* ws  = (float*)d_ws;

  // Workspace regions (lifetimes do not overlap within a region):
  float* c1   = ws;                          // R1: conv1 out (dead after conv2)
  float* dl   = ws;                          // R1: delta [b,l,d]
  float* c2   = ws + RSZ;                    // R2: conv2 out (dead after inproj)
  float* bmt  = ws + RSZ;                    // R2: BmT [b,l,16]
  float* cmt  = ws + RSZ + 1048576;          // R2: CmT [b,l,16]
  float* xpre = ws + 2 * RSZ;                // R3: pre-conv1d x [b,l,d] (dead after dwconv)
  float* Pb   = ws + 2 * RSZ;                // R3: chunk products
  float* Qb   = ws + 2 * RSZ + 2097152;      // R3
  float* H0b  = ws + 2 * RSZ + 4194304;      // R3
  float* zbuf = ws + 3 * RSZ;                // R4: z [b,l,d]
  float* ubuf = ws + 4 * RSZ;                // R5: u [b,l,d]
  float* Ab   = ws + 5 * RSZ;                // A = -exp(A_log)
  float* wT1  = Ab + 2048;
  float* wT2  = wT1 + 36864;

  k_prep<<<144, 256, 0, stream>>>(w1, w2, alog, wT1, wT2, Ab);
  k_conv<<<dim3(16, 2, 16), 256, 0, stream>>>(x, wT1, b1, c1);
  k_conv<<<dim3(16, 2, 16), 256, 0, stream>>>(c1, wT2, b2, c2);
  k_inproj<<<dim3(64, 4, 16), 256, 0, stream>>>(c2, win, xpre, zbuf);
  k_dwconv<<<8192, 256, 0, stream>>>(xpre, w1d, b1d, ubuf);
  k_xproj<<<256, 256, 0, stream>>>(ubuf, wxp, wdt, bdt, bmt, cmt, dl);
  k_scan1<<<dim3(NCHK, NB), 128, 0, stream>>>(dl, ubuf, bmt, Ab, Pb, Qb);
  k_scan2<<<dim3(8, NB), 256, 0, stream>>>(Pb, Qb, H0b);
  k_scan3<<<dim3(NCHK, NB), 128, 0, stream>>>(dl, ubuf, zbuf, bmt, cmt, Ab,
                                              H0b, dvec, wout, out);
}

// Round 3
// 297.146 us; speedup vs baseline: 1.7845x; 1.3729x over previous
//
#include <hip/hip_runtime.h>
#include <math.h>

// Problem constants (fixed by the reference)
#define NB   16      // batch
#define NCH  64      // C
#define NH   64      // H
#define NW   64      // W
#define NL   4096    // H*W
#define DIN  128     // D_INNER
#define DST  16      // D_STATE
#define DTR  4       // DT_RANK
#define NJ   256     // 2*D_INNER
#define NCHK 64      // scan chunks
#define CT   64      // chunk length (NCHK*CT == NL)

#define RSZ 8388608ull   // floats per workspace region

typedef _Float16 f16x8 __attribute__((ext_vector_type(8)));
typedef float    f32x4 __attribute__((ext_vector_type(4)));

// ---------------------------------------------------------------------------
// prep: A = -exp(A_log); conv weights (co,ci,3,3) -> f16 [t][co][ci]
// ---------------------------------------------------------------------------
__global__ void k_prep(const float* __restrict__ w1, const float* __restrict__ w2,
                       const float* __restrict__ alog,
                       _Float16* __restrict__ wf1, _Float16* __restrict__ wf2,
                       float* __restrict__ A1) {
  int i = blockIdx.x * 256 + threadIdx.x;
  if (i < 9 * 64 * 64) {
    int t  = i >> 12;
    int co = (i >> 6) & 63;
    int ci = i & 63;
    wf1[i] = (_Float16)w1[(co * 64 + ci) * 9 + t];
    wf2[i] = (_Float16)w2[(co * 64 + ci) * 9 + t];
  }
  if (i < DIN * DST) A1[i] = -__expf(alog[i]);
}

// ---------------------------------------------------------------------------
// conv3x3 + bias + leaky ReLU via f16 MFMA (fp32 accumulate).
// 9 shifted GEMMs: D[co][pix] += W_t[co][ci] * X[ci][pix+shift_t].
// Block: 2 output rows x 64 cols x 64 co, 4 waves (wave = (row, co-half)).
// X tile in LDS [4 rows][66 cols][72 ci-pad] f16 (ci contiguous -> b128 frags).
// W A-frags read per tap from L2 (all blocks share the 73.7 KB tensor).
// ---------------------------------------------------------------------------
__global__ __launch_bounds__(256, 2) void k_convmfma(
    const float* __restrict__ in, const _Float16* __restrict__ Wf,
    const float* __restrict__ bias, float* __restrict__ out) {
  __shared__ __align__(16) _Float16 xs[4][66][72];
  const int tid  = threadIdx.x;
  const int wv   = tid >> 6;
  const int lane = tid & 63;
  const int b    = blockIdx.y;
  const int h0   = blockIdx.x * 2;

  // stage X: wave wv stages halo row rr = wv (h = h0-1+wv) for all ci
  {
    const int rr = wv;
    const int h  = h0 - 1 + rr;
    const bool ok = (h >= 0) && (h < NH);
    for (int ci = 0; ci < NCH; ++ci) {
      float v = ok ? in[(((size_t)b * NCH + ci) * NH + h) * NW + lane] : 0.f;
      xs[rr][lane + 1][ci] = (_Float16)v;
      if (lane < 2) xs[rr][lane ? 65 : 0][ci] = (_Float16)0.f;
    }
  }
  __syncthreads();

  const int r      = wv & 1;        // output row within block
  const int cohalf = wv >> 1;       // 32-co half
  const int kgrp   = lane >> 4;     // k-group 0..3
  const int ln16   = lane & 15;

  f32x4 acc[2][4];
#pragma unroll
  for (int m = 0; m < 2; ++m)
#pragma unroll
    for (int f = 0; f < 4; ++f) acc[m][f] = (f32x4){0.f, 0.f, 0.f, 0.f};

  // A-frag base for this lane: co-row = cohalf*32 + m*16 + ln16
  const _Float16* wbase = Wf + (size_t)(cohalf * 32 + ln16) * 64 + kgrp * 8;

#pragma unroll
  for (int ts = 0; ts < 18; ++ts) {
    const int t  = ts >> 1;          // tap 0..8
    const int s  = ts & 1;           // k-step (ci 0..31 / 32..63)
    const int kh = t / 3;
    const int kw = t - kh * 3;
    f16x8 af[2];
#pragma unroll
    for (int m = 0; m < 2; ++m)
      af[m] = *(const f16x8*)(wbase + ((size_t)t * 64 + m * 16) * 64 + s * 32);
    f16x8 bf[4];
#pragma unroll
    for (int f = 0; f < 4; ++f)
      bf[f] = *(const f16x8*)&xs[r + kh][16 * f + kw + ln16][s * 32 + kgrp * 8];
#pragma unroll
    for (int m = 0; m < 2; ++m)
#pragma unroll
      for (int f = 0; f < 4; ++f)
        acc[m][f] = __builtin_amdgcn_mfma_f32_16x16x32_f16(af[m], bf[f],
                                                           acc[m][f], 0, 0, 0);
  }

  // epilogue: bias + leaky ReLU, store fp32
  float bv[2][4];
#pragma unroll
  for (int m = 0; m < 2; ++m)
#pragma unroll
    for (int reg = 0; reg < 4; ++reg)
      bv[m][reg] = bias[cohalf * 32 + m * 16 + kgrp * 4 + reg];
#pragma unroll
  for (int m = 0; m < 2; ++m) {
    const int cob = cohalf * 32 + m * 16 + kgrp * 4;
#pragma unroll
    for (int f = 0; f < 4; ++f) {
#pragma unroll
      for (int reg = 0; reg < 4; ++reg) {
        float v = acc[m][f][reg] + bv[m][reg];
        v = v >= 0.f ? v : 0.01f * v;
        out[(((size_t)b * NCH + cob + reg) * NH + h0 + r) * NW + 16 * f + ln16] = v;
      }
    }
  }
}

// ---------------------------------------------------------------------------
// in_proj: xz[b,l,j] = sum_c Y[b,c,l] * Win[c,j]
// output layout: xpre[b][l][d] (j<128), z[b][l][d] (j>=128)
// ---------------------------------------------------------------------------
__global__ __launch_bounds__(256) void k_inproj(
    const float* __restrict__ Y, const float* __restrict__ Win,
    float* __restrict__ xpre, float* __restrict__ z) {
  const int tid  = threadIdx.x;
  const int wv   = __builtin_amdgcn_readfirstlane(tid >> 6);
  const int lane = tid & 63;
  const int b    = blockIdx.z;
  const int l    = blockIdx.x * 64 + lane;
  const int j0   = blockIdx.y * 64 + wv * 16;
  const float* yp = Y + (size_t)b * NCH * NL + l;
  const float* wp = Win + j0;
  float acc[16];
#pragma unroll
  for (int j = 0; j < 16; ++j) acc[j] = 0.f;
  for (int c = 0; c < NCH; ++c) {
    const float yv = yp[(size_t)c * NL];
    const float* w = wp + c * NJ;
#pragma unroll
    for (int j = 0; j < 16; ++j) acc[j] = fmaf(yv, w[j], acc[j]);
  }
  float* outp = (j0 < DIN)
      ? (xpre + ((size_t)b * NL + l) * DIN + j0)
      : (z + ((size_t)b * NL + l) * DIN + (j0 - DIN));
#pragma unroll
  for (int j4 = 0; j4 < 4; ++j4)
    *(float4*)&outp[j4 * 4] = make_float4(acc[j4 * 4 + 0], acc[j4 * 4 + 1],
                                          acc[j4 * 4 + 2], acc[j4 * 4 + 3]);
}

// ---------------------------------------------------------------------------
// causal depthwise conv1d (k=4) + bias + silu, [b][l][d] layout.
// ---------------------------------------------------------------------------
__global__ void k_dwconv(const float* __restrict__ xpre,
                         const float* __restrict__ w1d,
                         const float* __restrict__ b1d,
                         float* __restrict__ u) {
  const int gid = blockIdx.x * 256 + threadIdx.x;   // total NB*NL*32
  const int d4  = gid & 31;
  const int bl  = gid >> 5;
  const int l   = bl & (NL - 1);
  const int d0  = d4 * 4;
  const float* xp = xpre + (size_t)bl * DIN + d0;
  float4 xk[4];
#pragma unroll
  for (int k = 0; k < 4; ++k) {
    const int lk = l - 3 + k;
    xk[k] = (lk >= 0) ? *(const float4*)&xp[(k - 3) * DIN]
                      : make_float4(0.f, 0.f, 0.f, 0.f);
  }
  float4 o;
  float* po = (float*)&o;
#pragma unroll
  for (int p = 0; p < 4; ++p) {
    const int d = d0 + p;
    float v = b1d[d];
    v = fmaf(w1d[d * 4 + 0], ((const float*)&xk[0])[p], v);
    v = fmaf(w1d[d * 4 + 1], ((const float*)&xk[1])[p], v);
    v = fmaf(w1d[d * 4 + 2], ((const float*)&xk[2])[p], v);
    v = fmaf(w1d[d * 4 + 3], ((const float*)&xk[3])[p], v);
    po[p] = __fdividef(v, 1.f + __expf(-v));   // silu
  }
  *(float4*)&u[(size_t)bl * DIN + d0] = o;
}

// ---------------------------------------------------------------------------
// x_proj + split + dt_proj + softplus, [b][l][d] layouts.
// ---------------------------------------------------------------------------
__global__ __launch_bounds__(256) void k_xproj(
    const float* __restrict__ u, const float* __restrict__ Wxp,
    const float* __restrict__ Wdt, const float* __restrict__ bdt,
    float* __restrict__ BmT, float* __restrict__ CmT,
    float* __restrict__ delta) {
  const int g = blockIdx.x * 256 + threadIdx.x;   // g = b*NL + l
  const float* up = u + (size_t)g * DIN;
  float dbc[36];
#pragma unroll
  for (int j = 0; j < 36; ++j) dbc[j] = 0.f;
  for (int d4 = 0; d4 < 32; ++d4) {
    const float4 uv = *(const float4*)&up[d4 * 4];
    const float* uvf = (const float*)&uv;
#pragma unroll
    for (int p = 0; p < 4; ++p) {
      const float* w = Wxp + (d4 * 4 + p) * 36;
      const float uu = uvf[p];
#pragma unroll
      for (int j = 0; j < 36; ++j) dbc[j] = fmaf(uu, w[j], dbc[j]);
    }
  }
  float* bp = BmT + (size_t)g * 16;
  float* cp = CmT + (size_t)g * 16;
#pragma unroll
  for (int n4 = 0; n4 < 4; ++n4) {
    *(float4*)&bp[n4 * 4] = make_float4(dbc[4 + n4 * 4], dbc[5 + n4 * 4],
                                        dbc[6 + n4 * 4], dbc[7 + n4 * 4]);
    *(float4*)&cp[n4 * 4] = make_float4(dbc[20 + n4 * 4], dbc[21 + n4 * 4],
                                        dbc[22 + n4 * 4], dbc[23 + n4 * 4]);
  }
  float* dp = delta + (size_t)g * DIN;
  for (int d4 = 0; d4 < 32; ++d4) {
    float4 o;
    float* po = (float*)&o;
#pragma unroll
    for (int p = 0; p < 4; ++p) {
      const int d = d4 * 4 + p;
      float s = bdt[d];
#pragma unroll
      for (int r2 = 0; r2 < DTR; ++r2) s = fmaf(dbc[r2], Wdt[r2 * DIN + d], s);
      po[p] = fmaxf(s, 0.f) + log1pf(expf(-fabsf(s)));   // softplus
    }
    *(float4*)&dp[d4 * 4] = o;
  }
}

// ---------------------------------------------------------------------------
// scan phase 1: per-chunk P = prod(a), Q = sum(prefix a * db * B)
// ---------------------------------------------------------------------------
__global__ __launch_bounds__(128) void k_scan1(
    const float* __restrict__ delta, const float* __restrict__ u,
    const float* __restrict__ BmT, const float* __restrict__ A1,
    float* __restrict__ P, float* __restrict__ Q) {
  const int d  = threadIdx.x;
  const int b  = blockIdx.y;
  const int ck = blockIdx.x;
  const int t0 = ck * CT;
  const float* dp = delta + ((size_t)b * NL + t0) * DIN + d;
  const float* up = u + ((size_t)b * NL + t0) * DIN + d;
  const float* bp = BmT + ((size_t)b * NL + t0) * 16;
  float a1[DST], Pr[DST], Qr[DST];
#pragma unroll
  for (int n = 0; n < 16; n += 4) {
    float4 t = *(const float4*)&A1[d * 16 + n];
    a1[n] = t.x; a1[n + 1] = t.y; a1[n + 2] = t.z; a1[n + 3] = t.w;
  }
#pragma unroll
  for (int n = 0; n < 16; ++n) { Pr[n] = 1.f; Qr[n] = 0.f; }
  for (int tt = 0; tt < CT; tt += 4) {
    float ld[4], lu[4];
#pragma unroll
    for (int q = 0; q < 4; ++q) {
      ld[q] = dp[(size_t)(tt + q) * DIN];
      lu[q] = up[(size_t)(tt + q) * DIN];
    }
#pragma unroll
    for (int q = 0; q < 4; ++q) {
      const float db = ld[q] * lu[q];
      const float* br = bp + (tt + q) * 16;
#pragma unroll
      for (int n = 0; n < 16; ++n) {
        const float a = __expf(ld[q] * a1[n]);
        Pr[n] *= a;
        Qr[n] = fmaf(a, Qr[n], db * br[n]);
      }
    }
  }
  const size_t o = (((size_t)b * NCHK + ck) * DIN + d) * 16;
#pragma unroll
  for (int n4 = 0; n4 < 4; ++n4) {
    *(float4*)&P[o + n4 * 4] = make_float4(Pr[n4 * 4], Pr[n4 * 4 + 1],
                                           Pr[n4 * 4 + 2], Pr[n4 * 4 + 3]);
    *(float4*)&Q[o + n4 * 4] = make_float4(Qr[n4 * 4], Qr[n4 * 4 + 1],
                                           Qr[n4 * 4 + 2], Qr[n4 * 4 + 3]);
  }
}

// ---------------------------------------------------------------------------
// scan phase 2: combine over chunks -> H0[b,ck,d,n]
// ---------------------------------------------------------------------------
__global__ __launch_bounds__(256) void k_scan2(
    const float* __restrict__ P, const float* __restrict__ Q,
    float* __restrict__ H0) {
  const int tid = threadIdx.x;
  const int b   = blockIdx.y;
  const int d   = blockIdx.x * 16 + (tid >> 4);
  const int n   = tid & 15;
  const size_t base = ((size_t)b * NCHK * DIN + d) * 16 + n;
  const size_t cs   = (size_t)DIN * 16;
  const float* pp = P + base;
  const float* qp = Q + base;
  float* hp = H0 + base;
  float h = 0.f;
  for (int c = 0; c < NCHK; c += 8) {
    float pv[8], qv[8];
#pragma unroll
    for (int k = 0; k < 8; ++k) {
      pv[k] = pp[k * cs];
      qv[k] = qp[k * cs];
    }
#pragma unroll
    for (int k = 0; k < 8; ++k) {
      hp[k * cs] = h;
      h = fmaf(pv[k], h, qv[k]);
    }
    pp += 8 * cs; qp += 8 * cs; hp += 8 * cs;
  }
}

// ---------------------------------------------------------------------------
// scan phase 3: replay chunk from H0, y = sum_n h*C, epilogue + out_proj
// ---------------------------------------------------------------------------
__global__ __launch_bounds__(128) void k_scan3(
    const float* __restrict__ delta, const float* __restrict__ u,
    const float* __restrict__ zb, const float* __restrict__ BmT,
    const float* __restrict__ CmT, const float* __restrict__ A1,
    const float* __restrict__ H0, const float* __restrict__ Dvec,
    const float* __restrict__ Wout, float* __restrict__ out) {
  __shared__ float yy[DIN * 67];
  const int d  = threadIdx.x;
  const int b  = blockIdx.y;
  const int ck = blockIdx.x;
  const int t0 = ck * CT;
  const float* dp = delta + ((size_t)b * NL + t0) * DIN + d;
  const float* up = u + ((size_t)b * NL + t0) * DIN + d;
  const float* zp = zb + ((size_t)b * NL + t0) * DIN + d;
  const float* bp = BmT + ((size_t)b * NL + t0) * 16;
  const float* cp = CmT + ((size_t)b * NL + t0) * 16;
  float a1[DST], h[DST];
  {
    const size_t ho = (((size_t)b * NCHK + ck) * DIN + d) * 16;
#pragma unroll
    for (int n = 0; n < 16; n += 4) {
      float4 t = *(const float4*)&A1[d * 16 + n];
      a1[n] = t.x; a1[n + 1] = t.y; a1[n + 2] = t.z; a1[n + 3] = t.w;
      float4 hv = *(const float4*)&H0[ho + n];
      h[n] = hv.x; h[n + 1] = hv.y; h[n + 2] = hv.z; h[n + 3] = hv.w;
    }
  }
  const float Dd = Dvec[d];
  for (int tt = 0; tt < CT; tt += 4) {
    float ld4[4], lu4[4], lz4[4];
#pragma unroll
    for (int q = 0; q < 4; ++q) {
      ld4[q] = dp[(size_t)(tt + q) * DIN];
      lu4[q] = up[(size_t)(tt + q) * DIN];
      lz4[q] = zp[(size_t)(tt + q) * DIN];
    }
#pragma unroll
    for (int q = 0; q < 4; ++q) {
      const float ld = ld4[q], lu = lu4[q], lz = lz4[q];
      const float db = ld * lu;
      const float* br = bp + (tt + q) * 16;
      const float* cr = cp + (tt + q) * 16;
      float y0 = 0.f, y1 = 0.f, y2 = 0.f, y3 = 0.f;
#pragma unroll
      for (int n = 0; n < 16; n += 4) {
        const float e0 = __expf(ld * a1[n + 0]);
        const float e1 = __expf(ld * a1[n + 1]);
        const float e2 = __expf(ld * a1[n + 2]);
        const float e3 = __expf(ld * a1[n + 3]);
        h[n + 0] = fmaf(e0, h[n + 0], db * br[n + 0]);
        h[n + 1] = fmaf(e1, h[n + 1], db * br[n + 1]);
        h[n + 2] = fmaf(e2, h[n + 2], db * br[n + 2]);
        h[n + 3] = fmaf(e3, h[n + 3], db * br[n + 3]);
        y0 = fmaf(h[n + 0], cr[n + 0], y0);
        y1 = fmaf(h[n + 1], cr[n + 1], y1);
        y2 = fmaf(h[n + 2], cr[n + 2], y2);
        y3 = fmaf(h[n + 3], cr[n + 3], y3);
      }
      const float yt = fmaf(lu, Dd, (y0 + y1) + (y2 + y3));
      const float sz = __fdividef(lz, 1.f + __expf(-lz));
      yy[d * 67 + tt + q] = yt * sz;
    }
  }
  __syncthreads();
  const int wv   = __builtin_amdgcn_readfirstlane(d >> 6);
  const int lane = d & 63;
  const int c0   = wv * 32;
  float acc[32];
#pragma unroll
  for (int j = 0; j < 32; ++j) acc[j] = 0.f;
  for (int dd = 0; dd < DIN; ++dd) {
    const float yv = yy[dd * 67 + lane];
    const float* w = Wout + dd * 64 + c0;
#pragma unroll
    for (int j = 0; j < 32; ++j) acc[j] = fmaf(yv, w[j], acc[j]);
  }
  float* op = out + (size_t)b * NCH * NL + t0 + lane;
#pragma unroll
  for (int j = 0; j < 32; ++j) op[(size_t)(c0 + j) * NL] = acc[j];
}

// ---------------------------------------------------------------------------
extern "C" void kernel_launch(void* const* d_in, const int* in_sizes, int n_in,
                              void* d_out, int out_size, void* d_ws,
                              size_t ws_size, hipStream_t stream) {
  (void)in_sizes; (void)n_in; (void)out_size; (void)ws_size;
  const float* x    = (const float*)d_in[0];
  const float* w1   = (const float*)d_in[1];
  const float* b1   = (const float*)d_in[2];
  const float* w2   = (const float*)d_in[3];
  const float* b2   = (const float*)d_in[4];
  const float* win  = (const float*)d_in[5];
  const float* w1d  = (const float*)d_in[6];
  const float* b1d  = (const float*)d_in[7];
  const float* wxp  = (const float*)d_in[8];
  const float* wdt  = (const float*)d_in[9];
  const float* bdt  = (const float*)d_in[10];
  const float* alog = (const float*)d_in[11];
  const float* dvec = (const float*)d_in[12];
  const float* wout = (const float*)d_in[13];
  float* out = (float*)d_out;
  float* ws  = (float*)d_ws;

  // Workspace regions (lifetimes do not overlap within a region):
  float* c1   = ws;                          // R1: conv1 out (dead after conv2)
  float* dl   = ws;                          // R1: delta [b,l,d]
  float* c2   = ws + RSZ;                    // R2: conv2 out (dead after inproj)
  float* bmt  = ws + RSZ;                    // R2: BmT [b,l,16]
  float* cmt  = ws + RSZ + 1048576;          // R2: CmT [b,l,16]
  float* xpre = ws + 2 * RSZ;                // R3: pre-conv1d x [b,l,d]
  float* Pb   = ws + 2 * RSZ;                // R3: chunk products
  float* Qb   = ws + 2 * RSZ + 2097152;      // R3
  float* H0b  = ws + 2 * RSZ + 4194304;      // R3
  float* zbuf = ws + 3 * RSZ;                // R4: z [b,l,d]
  float* ubuf = ws + 4 * RSZ;                // R5: u [b,l,d]
  float* Ab   = ws + 5 * RSZ;                // A = -exp(A_log)
  _Float16* wf1 = (_Float16*)(Ab + 2048);    // f16 conv weights [t][co][ci]
  _Float16* wf2 = wf1 + 9 * 64 * 64;

  k_prep<<<144, 256, 0, stream>>>(w1, w2, alog, wf1, wf2, Ab);
  k_convmfma<<<dim3(32, 16), 256, 0, stream>>>(x, wf1, b1, c1);
  k_convmfma<<<dim3(32, 16), 256, 0, stream>>>(c1, wf2, b2, c2);
  k_inproj<<<dim3(64, 4, 16), 256, 0, stream>>>(c2, win, xpre, zbuf);
  k_dwconv<<<8192, 256, 0, stream>>>(xpre, w1d, b1d, ubuf);
  k_xproj<<<256, 256, 0, stream>>>(ubuf, wxp, wdt, bdt, bmt, cmt, dl);
  k_scan1<<<dim3(NCHK, NB), 128, 0, stream>>>(dl, ubuf, bmt, Ab, Pb, Qb);
  k_scan2<<<dim3(8, NB), 256, 0, stream>>>(Pb, Qb, H0b);
  k_scan3<<<dim3(NCHK, NB), 128, 0, stream>>>(dl, ubuf, zbuf, bmt, cmt, Ab,
                                              H0b, dvec, wout, out);
}